// Round 1
// baseline (590.702 us; speedup 1.0000x reference)
//
#include <hip/hip_runtime.h>
#include <hip/hip_bf16.h>
#include <stdint.h>

typedef __bf16 bf16;
typedef __bf16 bf16x8 __attribute__((ext_vector_type(8)));
typedef float f32x4 __attribute__((ext_vector_type(4)));

#define T_SEQ 2048
#define DIM_ 512
#define NH_ 8
#define NKV_ 4
#define HD_ 64
#define BT_ (8 * T_SEQ) /* 16384 token rows */
#define NEG_INF (-1e30f)
#define EPS_ 1.1920928955078125e-07f

// workspace layout (bytes)
#define OFF_XB   (size_t)(0)
#define OFF_WQKV (size_t)(16777216)
#define OFF_WP   (size_t)(17825792)
#define OFF_COS  (size_t)(18350080)
#define OFF_SIN  (size_t)(18612224)
#define OFF_QT   (size_t)(18874368)
#define OFF_KT   (size_t)(35651584)
#define OFF_VT   (size_t)(44040192)
#define OFF_Y    (size_t)(52428800)
#define WS_NEEDED (size_t)(69206016)

__device__ inline void mfma16(f32x4& acc, bf16x8 a, bf16x8 b) {
    acc = __builtin_amdgcn_mfma_f32_16x16x32_bf16(a, b, acc, 0, 0, 0);
}

// ---------------- prep: fp32 -> bf16 casts + stacked W + rope tables ----------------
__global__ void prep_kernel(const float* __restrict__ x, const float* __restrict__ wq,
                            const float* __restrict__ wk, const float* __restrict__ wv,
                            const float* __restrict__ wp,
                            bf16* __restrict__ xb, bf16* __restrict__ wqkv,
                            bf16* __restrict__ wpb, float* __restrict__ cosT,
                            float* __restrict__ sinT) {
    int tid = blockIdx.x * blockDim.x + threadIdx.x;
    int stride = gridDim.x * blockDim.x;
    for (int i = tid; i < BT_ * DIM_; i += stride) xb[i] = (bf16)x[i];
    for (int i = tid; i < 1024 * 512; i += stride) {
        int j = i >> 9, k = i & 511;
        float v;
        if (j < 512) v = wq[i];
        else if (j < 768) v = wk[(j - 512) * 512 + k];
        else v = wv[(j - 768) * 512 + k];
        wqkv[i] = (bf16)v;
    }
    for (int i = tid; i < 512 * 512; i += stride) wpb[i] = (bf16)wp[i];
    for (int i = tid; i < T_SEQ * 32; i += stride) {
        int t = i >> 5, d = i & 31;
        float inv = powf(10000.0f, -(float)d * (1.0f / 32.0f));
        float f = (float)t * inv;
        cosT[i] = cosf(f);
        sinT[i] = sinf(f);
    }
}

// ---------------- QKV GEMM: out[i][j] = sum_k X[i][k]*Wqkv[j][k] ----------------
// 128x128 block tile, 4 waves (2x2), per-wave 64x64 = 4x4 acc tiles of 16x16.
// Direct-from-global fragment loads (X fully L3-resident; W tiny).
__global__ __launch_bounds__(256) void qkv_gemm(const bf16* __restrict__ A,
                                                const bf16* __restrict__ B,
                                                bf16* __restrict__ qt,
                                                bf16* __restrict__ kt,
                                                bf16* __restrict__ vt) {
    const int lane = threadIdx.x & 63, wid = threadIdx.x >> 6;
    const int wr = wid >> 1, wc = wid & 1;
    const int brow = blockIdx.x * 128, bcol = blockIdx.y * 128;
    const int lm = lane & 15, lk = (lane >> 4) * 8;
    f32x4 acc[4][4] = {};
    const bf16* Abase = A + (size_t)(brow + wr * 64 + lm) * DIM_ + lk;
    const bf16* Bbase = B + (size_t)(bcol + wc * 64 + lm) * DIM_ + lk;
    for (int k0 = 0; k0 < DIM_; k0 += 32) {
        bf16x8 af[4], bfr[4];
#pragma unroll
        for (int m = 0; m < 4; ++m) af[m] = *(const bf16x8*)(Abase + (size_t)m * 16 * DIM_ + k0);
#pragma unroll
        for (int n = 0; n < 4; ++n) bfr[n] = *(const bf16x8*)(Bbase + (size_t)n * 16 * DIM_ + k0);
#pragma unroll
        for (int m = 0; m < 4; ++m)
#pragma unroll
            for (int n = 0; n < 4; ++n) mfma16(acc[m][n], af[m], bfr[n]);
    }
#pragma unroll
    for (int m = 0; m < 4; ++m)
#pragma unroll
        for (int n = 0; n < 4; ++n)
#pragma unroll
            for (int r = 0; r < 4; ++r) {
                int i = brow + wr * 64 + m * 16 + ((lane >> 4) << 2) + r;
                int j = bcol + wc * 64 + n * 16 + lm;
                float v = acc[m][n][r];
                int b = i >> 11, t = i & 2047;
                if (j < 512) {
                    qt[(size_t)(((b << 3) + (j >> 6)) * T_SEQ + t) * HD_ + (j & 63)] = (bf16)v;
                } else if (j < 768) {
                    int jj = j - 512;
                    kt[(size_t)(((b << 2) + (jj >> 6)) * T_SEQ + t) * HD_ + (jj & 63)] = (bf16)v;
                } else {
                    int jj = j - 768;
                    // transposed V: vt[b][hkv][d][t]
                    vt[(size_t)(((b << 2) + (jj >> 6)) * HD_ + (jj & 63)) * T_SEQ + t] = (bf16)v;
                }
            }
}

// ---------------- RMSNorm (per 64-dim head row) + RoPE, in place on q and k ----------------
__global__ void rmsrope_kernel(bf16* __restrict__ qt, bf16* __restrict__ kt,
                               const float* __restrict__ cosT, const float* __restrict__ sinT) {
    const int rows_q = 8 * NH_ * T_SEQ;     // 131072
    const int rows_total = rows_q + 8 * NKV_ * T_SEQ; // 196608
    int lane = threadIdx.x & 63;
    int wave = threadIdx.x >> 6;
    int waves_per_grid = gridDim.x * (blockDim.x >> 6);
    for (int row = blockIdx.x * (blockDim.x >> 6) + wave; row < rows_total; row += waves_per_grid) {
        bf16* base;
        int t;
        if (row < rows_q) { base = qt + (size_t)row * HD_; t = row & (T_SEQ - 1); }
        else { int r2 = row - rows_q; base = kt + (size_t)r2 * HD_; t = r2 & (T_SEQ - 1); }
        float xv = (float)base[lane];
        float ss = xv * xv;
#pragma unroll
        for (int m = 1; m < 64; m <<= 1) ss += __shfl_xor(ss, m);
        float rinv = rsqrtf(ss * (1.0f / 64.0f) + EPS_);
        float xn = xv * rinv;
        float p = __shfl_xor(xn, 32);
        int d = lane & 31;
        float c = cosT[t * 32 + d], s = sinT[t * 32 + d];
        float out = (lane < 32) ? (xn * c + p * s) : (xn * c - p * s);
        base[lane] = (bf16)out;
    }
}

// ---------------- causal GQA flash attention ----------------
// grid: 64 (b,h) * 32 q-blocks. 4 independent waves per block, 16 q rows each.
__global__ __launch_bounds__(256) void attn_kernel(const bf16* __restrict__ qt,
                                                   const bf16* __restrict__ kt,
                                                   const bf16* __restrict__ vt,
                                                   bf16* __restrict__ y) {
    __shared__ bf16 p_lds[4][16][40]; // padded stride 40 (80B, 16B-aligned rows)
    const int lane = threadIdx.x & 63, wid = threadIdx.x >> 6;
    const int lm = lane & 15, lk = (lane >> 4) * 8;
    const int bh = blockIdx.x >> 5, qb = blockIdx.x & 31;
    const int b = bh >> 3, h = bh & 7, hv = h >> 1;
    const bf16* Q = qt + (size_t)bh * T_SEQ * HD_;
    const bf16* K = kt + (size_t)(b * NKV_ + hv) * T_SEQ * HD_;
    const bf16* V = vt + (size_t)(b * NKV_ + hv) * HD_ * T_SEQ;
    const int qw = qb * 64 + wid * 16;

    bf16x8 qf0 = *(const bf16x8*)(Q + (size_t)(qw + lm) * HD_ + lk);
    bf16x8 qf1 = *(const bf16x8*)(Q + (size_t)(qw + lm) * HD_ + 32 + lk);

    f32x4 o[4] = {};
    float mrow[4] = {NEG_INF, NEG_INF, NEG_INF, NEG_INF};
    float lrow[4] = {0.f, 0.f, 0.f, 0.f};

    const int ntiles = (qw + 15) / 32 + 1;
    for (int tk = 0; tk < ntiles; ++tk) {
        const int kv0 = tk * 32;
        f32x4 s0 = {}, s1 = {};
        {
            const bf16* Kb = K + (size_t)kv0 * HD_ + lk;
            bf16x8 k00 = *(const bf16x8*)(Kb + (size_t)lm * HD_);
            bf16x8 k01 = *(const bf16x8*)(Kb + (size_t)lm * HD_ + 32);
            bf16x8 k10 = *(const bf16x8*)(Kb + (size_t)(16 + lm) * HD_);
            bf16x8 k11 = *(const bf16x8*)(Kb + (size_t)(16 + lm) * HD_ + 32);
            mfma16(s0, qf0, k00); mfma16(s0, qf1, k01);
            mfma16(s1, qf0, k10); mfma16(s1, qf1, k11);
        }
        float p0[4], p1[4], alpha[4];
#pragma unroll
        for (int r = 0; r < 4; ++r) {
            int qrow = qw + ((lane >> 4) << 2) + r;
            float v0 = ((kv0 + lm) <= qrow) ? s0[r] * 0.125f : NEG_INF;
            float v1 = ((kv0 + 16 + lm) <= qrow) ? s1[r] * 0.125f : NEG_INF;
            float mx = fmaxf(v0, v1);
            mx = fmaxf(mx, __shfl_xor(mx, 1));
            mx = fmaxf(mx, __shfl_xor(mx, 2));
            mx = fmaxf(mx, __shfl_xor(mx, 4));
            mx = fmaxf(mx, __shfl_xor(mx, 8));
            float mnew = fmaxf(mrow[r], mx);
            alpha[r] = __expf(mrow[r] - mnew);
            float e0 = __expf(v0 - mnew);
            float e1 = __expf(v1 - mnew);
            p0[r] = e0; p1[r] = e1;
            float sr = e0 + e1;
            sr += __shfl_xor(sr, 1);
            sr += __shfl_xor(sr, 2);
            sr += __shfl_xor(sr, 4);
            sr += __shfl_xor(sr, 8);
            lrow[r] = lrow[r] * alpha[r] + sr;
            mrow[r] = mnew;
        }
#pragma unroll
        for (int n2 = 0; n2 < 4; ++n2)
#pragma unroll
            for (int r = 0; r < 4; ++r) o[n2][r] *= alpha[r];
        // P -> LDS (D-layout write), then re-read as A-fragment
        bf16* pl = &p_lds[wid][0][0];
        asm volatile("s_waitcnt lgkmcnt(0)" ::: "memory"); // prior pf read drained
#pragma unroll
        for (int r = 0; r < 4; ++r) {
            int row = ((lane >> 4) << 2) + r;
            pl[row * 40 + lm] = (bf16)p0[r];
            pl[row * 40 + 16 + lm] = (bf16)p1[r];
        }
        asm volatile("s_waitcnt lgkmcnt(0)" ::: "memory");
        __builtin_amdgcn_sched_barrier(0);
        bf16x8 pf = *(const bf16x8*)(pl + lm * 40 + lk);
#pragma unroll
        for (int n2 = 0; n2 < 4; ++n2) {
            bf16x8 vf = *(const bf16x8*)(V + (size_t)(n2 * 16 + lm) * T_SEQ + kv0 + lk);
            mfma16(o[n2], pf, vf);
        }
    }
#pragma unroll
    for (int n2 = 0; n2 < 4; ++n2)
#pragma unroll
        for (int r = 0; r < 4; ++r) {
            int t = qw + ((lane >> 4) << 2) + r;
            float val = o[n2][r] / lrow[r];
            y[(size_t)(b * T_SEQ + t) * DIM_ + h * HD_ + n2 * 16 + lm] = (bf16)val;
        }
}

// ---------------- output projection: out[i][j] = sum_k Y[i][k]*Wp[j][k] ----------------
__global__ __launch_bounds__(256) void proj_gemm(const bf16* __restrict__ A,
                                                 const bf16* __restrict__ B,
                                                 float* __restrict__ out) {
    const int lane = threadIdx.x & 63, wid = threadIdx.x >> 6;
    const int wr = wid >> 1, wc = wid & 1;
    const int brow = blockIdx.x * 128, bcol = blockIdx.y * 128;
    const int lm = lane & 15, lk = (lane >> 4) * 8;
    f32x4 acc[4][4] = {};
    const bf16* Abase = A + (size_t)(brow + wr * 64 + lm) * DIM_ + lk;
    const bf16* Bbase = B + (size_t)(bcol + wc * 64 + lm) * DIM_ + lk;
    for (int k0 = 0; k0 < DIM_; k0 += 32) {
        bf16x8 af[4], bfr[4];
#pragma unroll
        for (int m = 0; m < 4; ++m) af[m] = *(const bf16x8*)(Abase + (size_t)m * 16 * DIM_ + k0);
#pragma unroll
        for (int n = 0; n < 4; ++n) bfr[n] = *(const bf16x8*)(Bbase + (size_t)n * 16 * DIM_ + k0);
#pragma unroll
        for (int m = 0; m < 4; ++m)
#pragma unroll
            for (int n = 0; n < 4; ++n) mfma16(acc[m][n], af[m], bfr[n]);
    }
#pragma unroll
    for (int m = 0; m < 4; ++m)
#pragma unroll
        for (int n = 0; n < 4; ++n)
#pragma unroll
            for (int r = 0; r < 4; ++r) {
                int i = brow + wr * 64 + m * 16 + ((lane >> 4) << 2) + r;
                int j = bcol + wc * 64 + n * 16 + lm;
                out[(size_t)i * DIM_ + j] = acc[m][n][r];
            }
}

extern "C" void kernel_launch(void* const* d_in, const int* in_sizes, int n_in,
                              void* d_out, int out_size, void* d_ws, size_t ws_size,
                              hipStream_t stream) {
    const float* x  = (const float*)d_in[0];
    const float* wq = (const float*)d_in[1];
    const float* wk = (const float*)d_in[2];
    const float* wv = (const float*)d_in[3];
    const float* wp = (const float*)d_in[4];
    if (ws_size < WS_NEEDED) return; // loud failure instead of silent corruption

    char* ws = (char*)d_ws;
    bf16* xb    = (bf16*)(ws + OFF_XB);
    bf16* wqkv  = (bf16*)(ws + OFF_WQKV);
    bf16* wpb   = (bf16*)(ws + OFF_WP);
    float* cosT = (float*)(ws + OFF_COS);
    float* sinT = (float*)(ws + OFF_SIN);
    bf16* qt    = (bf16*)(ws + OFF_QT);
    bf16* kt    = (bf16*)(ws + OFF_KT);
    bf16* vt    = (bf16*)(ws + OFF_VT);
    bf16* y     = (bf16*)(ws + OFF_Y);

    prep_kernel<<<2048, 256, 0, stream>>>(x, wq, wk, wv, wp, xb, wqkv, wpb, cosT, sinT);

    dim3 g1(BT_ / 128, 1024 / 128);
    qkv_gemm<<<g1, 256, 0, stream>>>(xb, wqkv, qt, kt, vt);

    rmsrope_kernel<<<2048, 256, 0, stream>>>(qt, kt, cosT, sinT);

    attn_kernel<<<64 * 32, 256, 0, stream>>>(qt, kt, vt, y);

    dim3 g2(BT_ / 128, 512 / 128);
    proj_gemm<<<g2, 256, 0, stream>>>(y, wpb, (float*)d_out);
}

// Round 2
// 213.265 us; speedup vs baseline: 2.7698x; 2.7698x over previous
//
#include <hip/hip_runtime.h>
#include <hip/hip_bf16.h>
#include <stdint.h>

typedef __bf16 bf16;
typedef __bf16 bf16x8 __attribute__((ext_vector_type(8)));
typedef __bf16 bf16x4 __attribute__((ext_vector_type(4)));
typedef float f32x4 __attribute__((ext_vector_type(4)));

#define T_SEQ 2048
#define DIM_ 512
#define NH_ 8
#define NKV_ 4
#define HD_ 64
#define BT_ (8 * T_SEQ) /* 16384 token rows */
#define NEG_INF (-1e30f)
#define EPS_ 1.1920928955078125e-07f

// workspace layout (bytes)
#define OFF_XB   (size_t)(0)
#define OFF_WQKV (size_t)(16777216)
#define OFF_WP   (size_t)(17825792)
#define OFF_COS  (size_t)(18350080)
#define OFF_SIN  (size_t)(18612224)
#define OFF_QT   (size_t)(18874368)
#define OFF_KT   (size_t)(35651584)
#define OFF_VT   (size_t)(44040192)
#define OFF_Y    (size_t)(52428800)
#define WS_NEEDED (size_t)(69206016)

__device__ inline void mfma16(f32x4& acc, bf16x8 a, bf16x8 b) {
    acc = __builtin_amdgcn_mfma_f32_16x16x32_bf16(a, b, acc, 0, 0, 0);
}

// async global->LDS, 16B per lane. LDS dest is wave-uniform base + lane*16;
// the per-lane GLOBAL address carries the permutation (m173 pattern).
typedef const __attribute__((address_space(1))) uint8_t* gas_ptr;
typedef __attribute__((address_space(3))) uint8_t* las_ptr;
__device__ inline void gload16(const bf16* g, bf16* l) {
    __builtin_amdgcn_global_load_lds((gas_ptr)(const void*)g, (las_ptr)(void*)l, 16, 0, 0);
}

// ---------------- prep: fp32 -> bf16 casts + stacked W + rope tables ----------------
__global__ void prep_kernel(const float* __restrict__ x, const float* __restrict__ wq,
                            const float* __restrict__ wk, const float* __restrict__ wv,
                            const float* __restrict__ wp,
                            bf16* __restrict__ xb, bf16* __restrict__ wqkv,
                            bf16* __restrict__ wpb, float* __restrict__ cosT,
                            float* __restrict__ sinT) {
    int tid = blockIdx.x * blockDim.x + threadIdx.x;
    int stride = gridDim.x * blockDim.x;
    for (int i = tid; i < BT_ * DIM_; i += stride) xb[i] = (bf16)x[i];
    for (int i = tid; i < 1024 * 512; i += stride) {
        int j = i >> 9, k = i & 511;
        float v;
        if (j < 512) v = wq[i];
        else if (j < 768) v = wk[(j - 512) * 512 + k];
        else v = wv[(j - 768) * 512 + k];
        wqkv[i] = (bf16)v;
    }
    for (int i = tid; i < 512 * 512; i += stride) wpb[i] = (bf16)wp[i];
    for (int i = tid; i < T_SEQ * 32; i += stride) {
        int t = i >> 5, d = i & 31;
        float inv = powf(10000.0f, -(float)d * (1.0f / 32.0f));
        float f = (float)t * inv;
        cosT[i] = cosf(f);
        sinT[i] = sinf(f);
    }
}

// ---------------- QKV GEMM: out[i][j] = sum_k X[i][k]*Wqkv[j][k] ----------------
__global__ __launch_bounds__(256) void qkv_gemm(const bf16* __restrict__ A,
                                                const bf16* __restrict__ B,
                                                bf16* __restrict__ qt,
                                                bf16* __restrict__ kt,
                                                bf16* __restrict__ vt) {
    const int lane = threadIdx.x & 63, wid = threadIdx.x >> 6;
    const int wr = wid >> 1, wc = wid & 1;
    const int brow = blockIdx.x * 128, bcol = blockIdx.y * 128;
    const int lm = lane & 15, lk = (lane >> 4) * 8;
    f32x4 acc[4][4] = {};
    const bf16* Abase = A + (size_t)(brow + wr * 64 + lm) * DIM_ + lk;
    const bf16* Bbase = B + (size_t)(bcol + wc * 64 + lm) * DIM_ + lk;
    for (int k0 = 0; k0 < DIM_; k0 += 32) {
        bf16x8 af[4], bfr[4];
#pragma unroll
        for (int m = 0; m < 4; ++m) af[m] = *(const bf16x8*)(Abase + (size_t)m * 16 * DIM_ + k0);
#pragma unroll
        for (int n = 0; n < 4; ++n) bfr[n] = *(const bf16x8*)(Bbase + (size_t)n * 16 * DIM_ + k0);
#pragma unroll
        for (int m = 0; m < 4; ++m)
#pragma unroll
            for (int n = 0; n < 4; ++n) mfma16(acc[m][n], af[m], bfr[n]);
    }
#pragma unroll
    for (int m = 0; m < 4; ++m)
#pragma unroll
        for (int n = 0; n < 4; ++n)
#pragma unroll
            for (int r = 0; r < 4; ++r) {
                int i = brow + wr * 64 + m * 16 + ((lane >> 4) << 2) + r;
                int j = bcol + wc * 64 + n * 16 + lm;
                float v = acc[m][n][r];
                int b = i >> 11, t = i & 2047;
                if (j < 512) {
                    qt[(size_t)(((b << 3) + (j >> 6)) * T_SEQ + t) * HD_ + (j & 63)] = (bf16)v;
                } else if (j < 768) {
                    int jj = j - 512;
                    kt[(size_t)(((b << 2) + (jj >> 6)) * T_SEQ + t) * HD_ + (jj & 63)] = (bf16)v;
                } else {
                    int jj = j - 768;
                    // transposed V: vt[b][hkv][d][t]
                    vt[(size_t)(((b << 2) + (jj >> 6)) * HD_ + (jj & 63)) * T_SEQ + t] = (bf16)v;
                }
            }
}

// ---------------- RMSNorm (per 64-dim head row) + RoPE; q also pre-scaled by 1/8 ----------------
__global__ void rmsrope_kernel(bf16* __restrict__ qt, bf16* __restrict__ kt,
                               const float* __restrict__ cosT, const float* __restrict__ sinT) {
    const int rows_q = 8 * NH_ * T_SEQ;     // 131072
    const int rows_total = rows_q + 8 * NKV_ * T_SEQ; // 196608
    int lane = threadIdx.x & 63;
    int wave = threadIdx.x >> 6;
    int waves_per_grid = gridDim.x * (blockDim.x >> 6);
    for (int row = blockIdx.x * (blockDim.x >> 6) + wave; row < rows_total; row += waves_per_grid) {
        bf16* base;
        int t;
        bool isq = (row < rows_q);
        if (isq) { base = qt + (size_t)row * HD_; t = row & (T_SEQ - 1); }
        else { int r2 = row - rows_q; base = kt + (size_t)r2 * HD_; t = r2 & (T_SEQ - 1); }
        float xv = (float)base[lane];
        float ss = xv * xv;
#pragma unroll
        for (int m = 1; m < 64; m <<= 1) ss += __shfl_xor(ss, m);
        float rinv = rsqrtf(ss * (1.0f / 64.0f) + EPS_);
        float xn = xv * rinv;
        float p = __shfl_xor(xn, 32);
        int d = lane & 31;
        float c = cosT[t * 32 + d], s = sinT[t * 32 + d];
        float out = (lane < 32) ? (xn * c + p * s) : (xn * c - p * s);
        if (isq) out *= 0.125f; // fold 1/sqrt(HD) into q
        base[lane] = (bf16)out;
    }
}

// ---------------- causal GQA flash attention (swapped-operand, LDS-shared KV) ----------------
// grid: 16 q-panels (128 rows) x 64 (b,h); heavy panels first. 4 waves/block, 32 q-rows/wave.
// KV tile 64 staged fragment-linear via global_load_lds; frag reads are base+lane*16 (conflict-free).
__global__ __launch_bounds__(256) void attn_kernel(const bf16* __restrict__ qt,
                                                   const bf16* __restrict__ kt,
                                                   const bf16* __restrict__ vt,
                                                   bf16* __restrict__ y) {
    __shared__ bf16 Klds[4096];      // 8 frag-slots x 64 lanes x 8 elem
    __shared__ bf16 Vlds[4096];
    __shared__ bf16 Plds[4][32 * 72]; // per-wave P / O-transpose buffer, stride 72
    const int tid = threadIdx.x;
    const int lane = tid & 63, wid = tid >> 6;
    const int lm = lane & 15, hi = lane >> 4;
    const int bh = blockIdx.x & 63;
    const int p = 15 - (int)(blockIdx.x >> 6); // heavy-first
    const int b = bh >> 3, h = bh & 7, hv = h >> 1;
    const bf16* Q = qt + (size_t)bh * T_SEQ * HD_;
    const bf16* K = kt + (size_t)(b * NKV_ + hv) * T_SEQ * HD_;
    const bf16* V = vt + (size_t)(b * NKV_ + hv) * HD_ * T_SEQ;
    const int qB = p * 128;
    const int qw = qB + wid * 32;
    bf16* Pl = &Plds[wid][0];

    // Q fragments (B-side): lane holds Q[q=16*qm+lm][d = 32*kk + 8*hi + j]
    bf16x8 qf[2][2];
#pragma unroll
    for (int qm = 0; qm < 2; ++qm)
#pragma unroll
        for (int kk = 0; kk < 2; ++kk)
            qf[qm][kk] = *(const bf16x8*)(Q + (size_t)(qw + 16 * qm + lm) * HD_ + 32 * kk + 8 * hi);

    f32x4 o[2][4] = {};
    float mrow[2] = {NEG_INF, NEG_INF};
    float lrow[2] = {0.f, 0.f};

    const int nt = (qB >> 6) + 2;
    for (int t = 0; t < nt; ++t) {
        const int kv0 = t << 6;
        __syncthreads(); // previous tile's compute done before overwrite
#pragma unroll
        for (int c = 0; c < 2; ++c) {
            int i = c * 256 + tid;          // chunk id = frag-slot*64 + lane
            int n2 = i >> 6, l = i & 63;
            int gr = (n2 >> 1) * 16 + (l & 15);
            int gc = (n2 & 1) * 32 + (l >> 4) * 8;
            gload16(K + (size_t)(kv0 + gr) * HD_ + gc, Klds + i * 8);
            gload16(V + (size_t)gr * T_SEQ + kv0 + gc, Vlds + i * 8);
        }
        asm volatile("s_waitcnt vmcnt(0)" ::: "memory");
        __syncthreads();

        if (kv0 <= qw + 31) { // wave-uniform: skip fully-masked tiles
            // ---- QK^T (swapped): s[qm][n] rows = kv (16n+4hi+r), col = q (lm)
            f32x4 s[2][4] = {};
#pragma unroll
            for (int kk = 0; kk < 2; ++kk) {
                bf16x8 kf[4];
#pragma unroll
                for (int n = 0; n < 4; ++n)
                    kf[n] = *(const bf16x8*)(Klds + ((n * 2 + kk) * 64 + lane) * 8);
#pragma unroll
                for (int qm = 0; qm < 2; ++qm)
#pragma unroll
                    for (int n = 0; n < 4; ++n) mfma16(s[qm][n], kf[n], qf[qm][kk]);
            }
            const bool partial = (kv0 + 63 > qw);
#pragma unroll
            for (int qm = 0; qm < 2; ++qm) {
                const int qg = qw + 16 * qm + lm;
                float v[4][4];
#pragma unroll
                for (int n = 0; n < 4; ++n)
#pragma unroll
                    for (int r = 0; r < 4; ++r) {
                        float xv = s[qm][n][r];
                        if (partial)
                            xv = ((kv0 + 16 * n + 4 * hi + r) <= qg) ? xv : NEG_INF;
                        v[n][r] = xv;
                    }
                float mx = v[0][0];
#pragma unroll
                for (int n = 0; n < 4; ++n)
#pragma unroll
                    for (int r = 0; r < 4; ++r) mx = fmaxf(mx, v[n][r]);
                mx = fmaxf(mx, __shfl_xor(mx, 16));
                mx = fmaxf(mx, __shfl_xor(mx, 32));
                float mnew = fmaxf(mrow[qm], mx);
                float alpha = __expf(mrow[qm] - mnew);
                mrow[qm] = mnew;
                float ps = 0.f;
                bf16x4 pw[4];
#pragma unroll
                for (int n = 0; n < 4; ++n)
#pragma unroll
                    for (int r = 0; r < 4; ++r) {
                        float e = __expf(v[n][r] - mnew);
                        ps += e;
                        pw[n][r] = (bf16)e;
                    }
                ps += __shfl_xor(ps, 16);
                ps += __shfl_xor(ps, 32);
                lrow[qm] = lrow[qm] * alpha + ps;
#pragma unroll
                for (int n = 0; n < 4; ++n)
                    *(bf16x4*)(Pl + (16 * qm + lm) * 72 + 16 * n + 4 * hi) = pw[n];
#pragma unroll
                for (int nd = 0; nd < 4; ++nd) o[qm][nd] *= alpha;
            }
            // ---- PV (swapped): o[qm][nd] rows = d (16nd+4hi+r), col = q (lm)
#pragma unroll
            for (int kk = 0; kk < 2; ++kk) {
                bf16x8 vf[4], pf[2];
#pragma unroll
                for (int nd = 0; nd < 4; ++nd)
                    vf[nd] = *(const bf16x8*)(Vlds + ((nd * 2 + kk) * 64 + lane) * 8);
#pragma unroll
                for (int qm = 0; qm < 2; ++qm)
                    pf[qm] = *(const bf16x8*)(Pl + (16 * qm + lm) * 72 + 32 * kk + 8 * hi);
#pragma unroll
                for (int qm = 0; qm < 2; ++qm)
#pragma unroll
                    for (int nd = 0; nd < 4; ++nd) mfma16(o[qm][nd], vf[nd], pf[qm]);
            }
        }
    }

    // epilogue: normalize, transpose O^T->O through per-wave LDS, coalesced y write
#pragma unroll
    for (int qm = 0; qm < 2; ++qm) {
        float rcl = 1.0f / lrow[qm];
#pragma unroll
        for (int nd = 0; nd < 4; ++nd) {
            bf16x4 ov;
#pragma unroll
            for (int r = 0; r < 4; ++r) ov[r] = (bf16)(o[qm][nd][r] * rcl);
            *(bf16x4*)(Pl + (16 * qm + lm) * 72 + nd * 16 + 4 * hi) = ov;
        }
    }
#pragma unroll
    for (int qm = 0; qm < 2; ++qm)
#pragma unroll
        for (int it = 0; it < 2; ++it) {
            int chunk = it * 64 + lane;
            int row = chunk >> 3, dc = (chunk & 7) * 8;
            bf16x8 val = *(const bf16x8*)(Pl + (16 * qm + row) * 72 + dc);
            *(bf16x8*)(y + (size_t)(b * T_SEQ + qw + 16 * qm + row) * DIM_ + h * HD_ + dc) = val;
        }
}

// ---------------- output projection: out[i][j] = sum_k Y[i][k]*Wp[j][k] ----------------
__global__ __launch_bounds__(256) void proj_gemm(const bf16* __restrict__ A,
                                                 const bf16* __restrict__ B,
                                                 float* __restrict__ out) {
    const int lane = threadIdx.x & 63, wid = threadIdx.x >> 6;
    const int wr = wid >> 1, wc = wid & 1;
    const int brow = blockIdx.x * 128, bcol = blockIdx.y * 128;
    const int lm = lane & 15, lk = (lane >> 4) * 8;
    f32x4 acc[4][4] = {};
    const bf16* Abase = A + (size_t)(brow + wr * 64 + lm) * DIM_ + lk;
    const bf16* Bbase = B + (size_t)(bcol + wc * 64 + lm) * DIM_ + lk;
    for (int k0 = 0; k0 < DIM_; k0 += 32) {
        bf16x8 af[4], bfr[4];
#pragma unroll
        for (int m = 0; m < 4; ++m) af[m] = *(const bf16x8*)(Abase + (size_t)m * 16 * DIM_ + k0);
#pragma unroll
        for (int n = 0; n < 4; ++n) bfr[n] = *(const bf16x8*)(Bbase + (size_t)n * 16 * DIM_ + k0);
#pragma unroll
        for (int m = 0; m < 4; ++m)
#pragma unroll
            for (int n = 0; n < 4; ++n) mfma16(acc[m][n], af[m], bfr[n]);
    }
#pragma unroll
    for (int m = 0; m < 4; ++m)
#pragma unroll
        for (int n = 0; n < 4; ++n)
#pragma unroll
            for (int r = 0; r < 4; ++r) {
                int i = brow + wr * 64 + m * 16 + ((lane >> 4) << 2) + r;
                int j = bcol + wc * 64 + n * 16 + lm;
                out[(size_t)i * DIM_ + j] = acc[m][n][r];
            }
}

extern "C" void kernel_launch(void* const* d_in, const int* in_sizes, int n_in,
                              void* d_out, int out_size, void* d_ws, size_t ws_size,
                              hipStream_t stream) {
    const float* x  = (const float*)d_in[0];
    const float* wq = (const float*)d_in[1];
    const float* wk = (const float*)d_in[2];
    const float* wv = (const float*)d_in[3];
    const float* wp = (const float*)d_in[4];
    if (ws_size < WS_NEEDED) return;

    char* ws = (char*)d_ws;
    bf16* xb    = (bf16*)(ws + OFF_XB);
    bf16* wqkv  = (bf16*)(ws + OFF_WQKV);
    bf16* wpb   = (bf16*)(ws + OFF_WP);
    float* cosT = (float*)(ws + OFF_COS);
    float* sinT = (float*)(ws + OFF_SIN);
    bf16* qt    = (bf16*)(ws + OFF_QT);
    bf16* kt    = (bf16*)(ws + OFF_KT);
    bf16* vt    = (bf16*)(ws + OFF_VT);
    bf16* y     = (bf16*)(ws + OFF_Y);

    prep_kernel<<<2048, 256, 0, stream>>>(x, wq, wk, wv, wp, xb, wqkv, wpb, cosT, sinT);

    dim3 g1(BT_ / 128, 1024 / 128);
    qkv_gemm<<<g1, 256, 0, stream>>>(xb, wqkv, qt, kt, vt);

    rmsrope_kernel<<<2048, 256, 0, stream>>>(qt, kt, cosT, sinT);

    attn_kernel<<<dim3(16 * 64), 256, 0, stream>>>(qt, kt, vt, y);

    dim3 g2(BT_ / 128, 512 / 128);
    proj_gemm<<<g2, 256, 0, stream>>>(y, wpb, (float*)d_out);
}

// Round 3
// 181.280 us; speedup vs baseline: 3.2585x; 1.1764x over previous
//
#include <hip/hip_runtime.h>
#include <hip/hip_bf16.h>
#include <stdint.h>

typedef __bf16 bf16;
typedef __bf16 bf16x8 __attribute__((ext_vector_type(8)));
typedef __bf16 bf16x4 __attribute__((ext_vector_type(4)));
typedef float f32x4 __attribute__((ext_vector_type(4)));

#define T_SEQ 2048
#define DIM_ 512
#define NH_ 8
#define NKV_ 4
#define HD_ 64
#define BT_ (8 * T_SEQ) /* 16384 token rows */
#define NEG_INF (-1e30f)
#define EPS_ 1.1920928955078125e-07f
#define QSCALE 0.18033688011112042f /* 0.125 * log2(e): attn uses exp2 */

// workspace layout (bytes)
#define OFF_XB   (size_t)(0)
#define OFF_WQKV (size_t)(16777216)
#define OFF_WP   (size_t)(17825792)
#define OFF_COS  (size_t)(18350080)
#define OFF_SIN  (size_t)(18612224)
#define OFF_QT   (size_t)(18874368)
#define OFF_KT   (size_t)(35651584)
#define OFF_VT   (size_t)(44040192)
#define OFF_Y    (size_t)(52428800)
#define WS_NEEDED (size_t)(69206016)

__device__ inline void mfma16(f32x4& acc, bf16x8 a, bf16x8 b) {
    acc = __builtin_amdgcn_mfma_f32_16x16x32_bf16(a, b, acc, 0, 0, 0);
}

// async global->LDS, 16B per lane. LDS dest is wave-uniform base + lane*16;
// the per-lane GLOBAL address carries the permutation (m173 pattern).
typedef const __attribute__((address_space(1))) uint8_t* gas_ptr;
typedef __attribute__((address_space(3))) uint8_t* las_ptr;
__device__ inline void gload16(const bf16* g, bf16* l) {
    __builtin_amdgcn_global_load_lds((gas_ptr)(const void*)g, (las_ptr)(void*)l, 16, 0, 0);
}

// ---------------- prep: fp32 -> bf16 casts + stacked W + rope tables ----------------
__global__ void prep_kernel(const float* __restrict__ x, const float* __restrict__ wq,
                            const float* __restrict__ wk, const float* __restrict__ wv,
                            const float* __restrict__ wp,
                            bf16* __restrict__ xb, bf16* __restrict__ wqkv,
                            bf16* __restrict__ wpb, float* __restrict__ cosT,
                            float* __restrict__ sinT) {
    int tid = blockIdx.x * blockDim.x + threadIdx.x;
    int stride = gridDim.x * blockDim.x;
    for (int i = tid; i < BT_ * DIM_; i += stride) xb[i] = (bf16)x[i];
    for (int i = tid; i < 1024 * 512; i += stride) {
        int j = i >> 9, k = i & 511;
        float v;
        if (j < 512) v = wq[i];
        else if (j < 768) v = wk[(j - 512) * 512 + k];
        else v = wv[(j - 768) * 512 + k];
        wqkv[i] = (bf16)v;
    }
    for (int i = tid; i < 512 * 512; i += stride) wpb[i] = (bf16)wp[i];
    for (int i = tid; i < T_SEQ * 32; i += stride) {
        int t = i >> 5, d = i & 31;
        float inv = powf(10000.0f, -(float)d * (1.0f / 32.0f));
        float f = (float)t * inv;
        cosT[i] = cosf(f);
        sinT[i] = sinf(f);
    }
}

// ---------------- QKV GEMM + fused RMSNorm + RoPE epilogue ----------------
// m97-style: 128x128 tile, BK=64, fragment-linear LDS staging via global_load_lds.
// Epilogue: per-wave 64x64 output tile; for q/k do in-register RMSNorm (+shfl over
// 16-lane groups) + RoPE (pairs (n,n+2) are in-lane), q pre-scaled by 0.125*log2e;
// store through per-wave LDS transpose for coalesced 128B rows (q/k row-major,
// v transposed [d][t]).
__global__ __launch_bounds__(256) void qkv_gemm(const bf16* __restrict__ A,
                                                const bf16* __restrict__ B,
                                                bf16* __restrict__ qt,
                                                bf16* __restrict__ kt,
                                                bf16* __restrict__ vt,
                                                const float* __restrict__ cosT,
                                                const float* __restrict__ sinT) {
    __shared__ __align__(16) char smem[34816]; // loop: A(16K)+B(16K); epilogue: 4x 64x66 bf16
    bf16* As = (bf16*)smem;
    bf16* Bs = (bf16*)(smem + 16384);
    const int tid = threadIdx.x, lane = tid & 63, wid = tid >> 6;
    const int wr = wid >> 1, wc = wid & 1;
    const int lm = lane & 15, hi = lane >> 4;
    const int bid = blockIdx.x;
    const int swz = (bid & 7) * 128 + (bid >> 3); // XCD swizzle: each XCD owns a col stripe
    const int brow = (swz & 127) * 128;
    const int bcol = (swz >> 7) * 128;

    f32x4 acc[4][4] = {};
    for (int k0 = 0; k0 < 512; k0 += 64) {
        __syncthreads();
#pragma unroll
        for (int i = 0; i < 4; ++i) {
            int c = i * 256 + tid;
            int slot = c >> 6, l = c & 63;
            int row = (slot >> 1) * 16 + (l & 15);
            int kc = (slot & 1) * 32 + (l >> 4) * 8;
            gload16(A + (size_t)(brow + row) * 512 + k0 + kc, As + c * 8);
            gload16(B + (size_t)(bcol + row) * 512 + k0 + kc, Bs + c * 8);
        }
        asm volatile("s_waitcnt vmcnt(0)" ::: "memory");
        __syncthreads();
#pragma unroll
        for (int kk = 0; kk < 2; ++kk) {
            bf16x8 af[4], bfr[4];
#pragma unroll
            for (int m = 0; m < 4; ++m)
                af[m] = *(const bf16x8*)(As + (((wr * 4 + m) * 2 + kk) * 64 + lane) * 8);
#pragma unroll
            for (int n = 0; n < 4; ++n)
                bfr[n] = *(const bf16x8*)(Bs + (((wc * 4 + n) * 2 + kk) * 64 + lane) * 8);
            __builtin_amdgcn_s_setprio(1);
#pragma unroll
            for (int m = 0; m < 4; ++m)
#pragma unroll
                for (int n = 0; n < 4; ++n) mfma16(acc[m][n], af[m], bfr[n]);
            __builtin_amdgcn_s_setprio(0);
        }
    }
    __syncthreads(); // staging reads complete; smem now the transpose buffer

    bf16* Tb = (bf16*)smem + wid * 4224; // 64 x 66 per wave
    const int wcol = bcol + wc * 64;     // 64-aligned -> whole wave is one head type
    const int ctype = (wcol < 512) ? 0 : (wcol < 768 ? 1 : 2);

    if (ctype < 2) {
#pragma unroll
        for (int m = 0; m < 4; ++m)
#pragma unroll
            for (int r = 0; r < 4; ++r) {
                float v0 = acc[m][0][r], v1 = acc[m][1][r];
                float v2 = acc[m][2][r], v3 = acc[m][3][r];
                float ss = v0 * v0 + v1 * v1 + v2 * v2 + v3 * v3;
                ss += __shfl_xor(ss, 1);
                ss += __shfl_xor(ss, 2);
                ss += __shfl_xor(ss, 4);
                ss += __shfl_xor(ss, 8);
                float rinv = rsqrtf(ss * (1.0f / 64.0f) + EPS_);
                v0 *= rinv; v1 *= rinv; v2 *= rinv; v3 *= rinv;
                int rl = m * 16 + hi * 4 + r;
                int t = (brow + wr * 64 + rl) & (T_SEQ - 1);
                float c0 = cosT[t * 32 + lm], s0 = sinT[t * 32 + lm];
                float c1 = cosT[t * 32 + 16 + lm], s1 = sinT[t * 32 + 16 + lm];
                float o0 = v0 * c0 + v2 * s0;
                float o2 = v2 * c0 - v0 * s0;
                float o1 = v1 * c1 + v3 * s1;
                float o3 = v3 * c1 - v1 * s1;
                if (ctype == 0) { o0 *= QSCALE; o1 *= QSCALE; o2 *= QSCALE; o3 *= QSCALE; }
                Tb[rl * 66 + lm]      = (bf16)o0;
                Tb[rl * 66 + 16 + lm] = (bf16)o1;
                Tb[rl * 66 + 32 + lm] = (bf16)o2;
                Tb[rl * 66 + 48 + lm] = (bf16)o3;
            }
    } else {
#pragma unroll
        for (int m = 0; m < 4; ++m)
#pragma unroll
            for (int n = 0; n < 4; ++n)
#pragma unroll
                for (int r = 0; r < 4; ++r)
                    Tb[(n * 16 + lm) * 66 + m * 16 + hi * 4 + r] = (bf16)acc[m][n][r];
    }
    __syncthreads();

    const int i0 = brow + wr * 64;
    const int b = i0 >> 11, tt = i0 & (T_SEQ - 1);
#pragma unroll
    for (int p = 0; p < 8; ++p) {
        int row = p * 8 + (lane >> 3);
        int ch = lane & 7;
        bf16x8 val = *(const bf16x8*)(Tb + row * 66 + ch * 8);
        if (ctype == 0) {
            int head = wcol >> 6;
            *(bf16x8*)(qt + ((size_t)((b << 3) + head) * T_SEQ + tt + row) * 64 + ch * 8) = val;
        } else if (ctype == 1) {
            int head = (wcol - 512) >> 6;
            *(bf16x8*)(kt + ((size_t)((b << 2) + head) * T_SEQ + tt + row) * 64 + ch * 8) = val;
        } else {
            int head = (wcol - 768) >> 6;
            *(bf16x8*)(vt + ((size_t)((b << 2) + head) * 64 + row) * T_SEQ + tt + ch * 8) = val;
        }
    }
}

// ---------------- causal GQA flash attention (swapped-operand, LDS-shared KV) ----------------
__global__ __launch_bounds__(256) void attn_kernel(const bf16* __restrict__ qt,
                                                   const bf16* __restrict__ kt,
                                                   const bf16* __restrict__ vt,
                                                   bf16* __restrict__ y) {
    __shared__ bf16 Klds[4096];      // 8 frag-slots x 64 lanes x 8 elem
    __shared__ bf16 Vlds[4096];
    __shared__ bf16 Plds[4][32 * 72]; // per-wave P / O-transpose buffer, stride 72
    const int tid = threadIdx.x;
    const int lane = tid & 63, wid = tid >> 6;
    const int lm = lane & 15, hi = lane >> 4;
    const int bh = blockIdx.x & 63;
    const int p = 15 - (int)(blockIdx.x >> 6); // heavy-first
    const int b = bh >> 3, h = bh & 7, hv = h >> 1;
    const bf16* Q = qt + (size_t)bh * T_SEQ * HD_;
    const bf16* K = kt + (size_t)(b * NKV_ + hv) * T_SEQ * HD_;
    const bf16* V = vt + (size_t)(b * NKV_ + hv) * HD_ * T_SEQ;
    const int qB = p * 128;
    const int qw = qB + wid * 32;
    bf16* Pl = &Plds[wid][0];

    // Q fragments (B-side): lane holds Q[q=16*qm+lm][d = 32*kk + 8*hi + j]
    bf16x8 qf[2][2];
#pragma unroll
    for (int qm = 0; qm < 2; ++qm)
#pragma unroll
        for (int kk = 0; kk < 2; ++kk)
            qf[qm][kk] = *(const bf16x8*)(Q + (size_t)(qw + 16 * qm + lm) * HD_ + 32 * kk + 8 * hi);

    f32x4 o[2][4] = {};
    float mrow[2] = {NEG_INF, NEG_INF};
    float lrow[2] = {0.f, 0.f};

    const int nt = (qB >> 6) + 2;
    for (int t = 0; t < nt; ++t) {
        const int kv0 = t << 6;
        __syncthreads(); // previous tile's compute done before overwrite
#pragma unroll
        for (int c = 0; c < 2; ++c) {
            int i = c * 256 + tid;          // chunk id = frag-slot*64 + lane
            int n2 = i >> 6, l = i & 63;
            int gr = (n2 >> 1) * 16 + (l & 15);
            int gc = (n2 & 1) * 32 + (l >> 4) * 8;
            gload16(K + (size_t)(kv0 + gr) * HD_ + gc, Klds + i * 8);
            gload16(V + (size_t)gr * T_SEQ + kv0 + gc, Vlds + i * 8);
        }
        asm volatile("s_waitcnt vmcnt(0)" ::: "memory");
        __syncthreads();

        if (kv0 <= qw + 31) { // wave-uniform: skip fully-masked tiles
            // ---- QK^T (swapped): s[qm][n] rows = kv (16n+4hi+r), col = q (lm)
            f32x4 s[2][4] = {};
#pragma unroll
            for (int kk = 0; kk < 2; ++kk) {
                bf16x8 kf[4];
#pragma unroll
                for (int n = 0; n < 4; ++n)
                    kf[n] = *(const bf16x8*)(Klds + ((n * 2 + kk) * 64 + lane) * 8);
                __builtin_amdgcn_s_setprio(1);
#pragma unroll
                for (int qm = 0; qm < 2; ++qm)
#pragma unroll
                    for (int n = 0; n < 4; ++n) mfma16(s[qm][n], kf[n], qf[qm][kk]);
                __builtin_amdgcn_s_setprio(0);
            }
            const bool partial = (kv0 + 63 > qw);
#pragma unroll
            for (int qm = 0; qm < 2; ++qm) {
                const int qg = qw + 16 * qm + lm;
                float v[4][4];
#pragma unroll
                for (int n = 0; n < 4; ++n)
#pragma unroll
                    for (int r = 0; r < 4; ++r) {
                        float xv = s[qm][n][r];
                        if (partial)
                            xv = ((kv0 + 16 * n + 4 * hi + r) <= qg) ? xv : NEG_INF;
                        v[n][r] = xv;
                    }
                float m0 = fmaxf(fmaxf(v[0][0], v[0][1]), fmaxf(v[0][2], v[0][3]));
                float m1 = fmaxf(fmaxf(v[1][0], v[1][1]), fmaxf(v[1][2], v[1][3]));
                float m2 = fmaxf(fmaxf(v[2][0], v[2][1]), fmaxf(v[2][2], v[2][3]));
                float m3 = fmaxf(fmaxf(v[3][0], v[3][1]), fmaxf(v[3][2], v[3][3]));
                float mx = fmaxf(fmaxf(m0, m1), fmaxf(m2, m3));
                mx = fmaxf(mx, __shfl_xor(mx, 16));
                mx = fmaxf(mx, __shfl_xor(mx, 32));
                // defer-max (T13): skip O/l rescale when max growth <= 8 (P <= 2^8)
                if (!__all(mx <= mrow[qm] + 8.0f)) {
                    float mnew = fmaxf(mrow[qm], mx);
                    float alpha = exp2f(mrow[qm] - mnew);
                    mrow[qm] = mnew;
                    lrow[qm] *= alpha;
#pragma unroll
                    for (int nd = 0; nd < 4; ++nd) o[qm][nd] *= alpha;
                }
                float ps = 0.f;
                bf16x4 pw[4];
#pragma unroll
                for (int n = 0; n < 4; ++n)
#pragma unroll
                    for (int r = 0; r < 4; ++r) {
                        float e = exp2f(v[n][r] - mrow[qm]);
                        ps += e;
                        pw[n][r] = (bf16)e;
                    }
                ps += __shfl_xor(ps, 16);
                ps += __shfl_xor(ps, 32);
                lrow[qm] += ps;
#pragma unroll
                for (int n = 0; n < 4; ++n)
                    *(bf16x4*)(Pl + (16 * qm + lm) * 72 + 16 * n + 4 * hi) = pw[n];
            }
            // ---- PV (swapped): o[qm][nd] rows = d (16nd+4hi+r), col = q (lm)
#pragma unroll
            for (int kk = 0; kk < 2; ++kk) {
                bf16x8 vf[4], pf[2];
#pragma unroll
                for (int nd = 0; nd < 4; ++nd)
                    vf[nd] = *(const bf16x8*)(Vlds + ((nd * 2 + kk) * 64 + lane) * 8);
#pragma unroll
                for (int qm = 0; qm < 2; ++qm)
                    pf[qm] = *(const bf16x8*)(Pl + (16 * qm + lm) * 72 + 32 * kk + 8 * hi);
                __builtin_amdgcn_s_setprio(1);
#pragma unroll
                for (int qm = 0; qm < 2; ++qm)
#pragma unroll
                    for (int nd = 0; nd < 4; ++nd) mfma16(o[qm][nd], vf[nd], pf[qm]);
                __builtin_amdgcn_s_setprio(0);
            }
        }
    }

    // epilogue: normalize, transpose O^T->O through per-wave LDS, coalesced y write
#pragma unroll
    for (int qm = 0; qm < 2; ++qm) {
        float rcl = 1.0f / lrow[qm];
#pragma unroll
        for (int nd = 0; nd < 4; ++nd) {
            bf16x4 ov;
#pragma unroll
            for (int r = 0; r < 4; ++r) ov[r] = (bf16)(o[qm][nd][r] * rcl);
            *(bf16x4*)(Pl + (16 * qm + lm) * 72 + nd * 16 + 4 * hi) = ov;
        }
    }
#pragma unroll
    for (int qm = 0; qm < 2; ++qm)
#pragma unroll
        for (int it = 0; it < 2; ++it) {
            int chunk = it * 64 + lane;
            int row = chunk >> 3, dc = (chunk & 7) * 8;
            bf16x8 val = *(const bf16x8*)(Pl + (16 * qm + row) * 72 + dc);
            *(bf16x8*)(y + (size_t)(b * T_SEQ + qw + 16 * qm + row) * DIM_ + h * HD_ + dc) = val;
        }
}

// ---------------- output projection: out[i][j] = sum_k Y[i][k]*Wp[j][k] ----------------
__global__ __launch_bounds__(256) void proj_gemm(const bf16* __restrict__ A,
                                                 const bf16* __restrict__ B,
                                                 float* __restrict__ out) {
    __shared__ __align__(16) char smem[32768];
    bf16* As = (bf16*)smem;
    bf16* Bs = (bf16*)(smem + 16384);
    const int tid = threadIdx.x, lane = tid & 63, wid = tid >> 6;
    const int wr = wid >> 1, wc = wid & 1;
    const int lm = lane & 15, hi = lane >> 4;
    const int bid = blockIdx.x;
    const int swz = (bid & 7) * 64 + (bid >> 3);
    const int brow = (swz & 127) * 128;
    const int bcol = (swz >> 7) * 128;

    f32x4 acc[4][4] = {};
    for (int k0 = 0; k0 < 512; k0 += 64) {
        __syncthreads();
#pragma unroll
        for (int i = 0; i < 4; ++i) {
            int c = i * 256 + tid;
            int slot = c >> 6, l = c & 63;
            int row = (slot >> 1) * 16 + (l & 15);
            int kc = (slot & 1) * 32 + (l >> 4) * 8;
            gload16(A + (size_t)(brow + row) * 512 + k0 + kc, As + c * 8);
            gload16(B + (size_t)(bcol + row) * 512 + k0 + kc, Bs + c * 8);
        }
        asm volatile("s_waitcnt vmcnt(0)" ::: "memory");
        __syncthreads();
#pragma unroll
        for (int kk = 0; kk < 2; ++kk) {
            bf16x8 af[4], bfr[4];
#pragma unroll
            for (int m = 0; m < 4; ++m)
                af[m] = *(const bf16x8*)(As + (((wr * 4 + m) * 2 + kk) * 64 + lane) * 8);
#pragma unroll
            for (int n = 0; n < 4; ++n)
                bfr[n] = *(const bf16x8*)(Bs + (((wc * 4 + n) * 2 + kk) * 64 + lane) * 8);
            __builtin_amdgcn_s_setprio(1);
#pragma unroll
            for (int m = 0; m < 4; ++m)
#pragma unroll
                for (int n = 0; n < 4; ++n) mfma16(acc[m][n], af[m], bfr[n]);
            __builtin_amdgcn_s_setprio(0);
        }
    }
#pragma unroll
    for (int m = 0; m < 4; ++m)
#pragma unroll
        for (int n = 0; n < 4; ++n)
#pragma unroll
            for (int r = 0; r < 4; ++r) {
                int i = brow + wr * 64 + m * 16 + hi * 4 + r;
                int j = bcol + wc * 64 + n * 16 + lm;
                out[(size_t)i * DIM_ + j] = acc[m][n][r];
            }
}

extern "C" void kernel_launch(void* const* d_in, const int* in_sizes, int n_in,
                              void* d_out, int out_size, void* d_ws, size_t ws_size,
                              hipStream_t stream) {
    const float* x  = (const float*)d_in[0];
    const float* wq = (const float*)d_in[1];
    const float* wk = (const float*)d_in[2];
    const float* wv = (const float*)d_in[3];
    const float* wp = (const float*)d_in[4];
    if (ws_size < WS_NEEDED) return;

    char* ws = (char*)d_ws;
    bf16* xb    = (bf16*)(ws + OFF_XB);
    bf16* wqkv  = (bf16*)(ws + OFF_WQKV);
    bf16* wpb   = (bf16*)(ws + OFF_WP);
    float* cosT = (float*)(ws + OFF_COS);
    float* sinT = (float*)(ws + OFF_SIN);
    bf16* qt    = (bf16*)(ws + OFF_QT);
    bf16* kt    = (bf16*)(ws + OFF_KT);
    bf16* vt    = (bf16*)(ws + OFF_VT);
    bf16* y     = (bf16*)(ws + OFF_Y);

    prep_kernel<<<2048, 256, 0, stream>>>(x, wq, wk, wv, wp, xb, wqkv, wpb, cosT, sinT);

    qkv_gemm<<<1024, 256, 0, stream>>>(xb, wqkv, qt, kt, vt, cosT, sinT);

    attn_kernel<<<dim3(16 * 64), 256, 0, stream>>>(qt, kt, vt, y);

    proj_gemm<<<512, 256, 0, stream>>>(y, wpb, (float*)d_out);
}

// Round 4
// 170.742 us; speedup vs baseline: 3.4596x; 1.0617x over previous
//
#include <hip/hip_runtime.h>
#include <hip/hip_bf16.h>
#include <stdint.h>

typedef __bf16 bf16;
typedef __bf16 bf16x8 __attribute__((ext_vector_type(8)));
typedef __bf16 bf16x4 __attribute__((ext_vector_type(4)));
typedef float f32x4 __attribute__((ext_vector_type(4)));

#define T_SEQ 2048
#define DIM_ 512
#define NH_ 8
#define NKV_ 4
#define HD_ 64
#define BT_ (8 * T_SEQ) /* 16384 token rows */
#define NEG_INF (-1e30f)
#define EPS_ 1.1920928955078125e-07f
#define QSCALE 0.18033688011112042f /* 0.125 * log2(e): attn uses exp2 */
#define SMAX 12.0f /* fixed softmax max: |score| <= 64*0.125*log2e = 11.54 < 12 */

// workspace layout (bytes)
#define OFF_XB   (size_t)(0)
#define OFF_WQKV (size_t)(16777216)
#define OFF_WP   (size_t)(17825792)
#define OFF_COS  (size_t)(18350080)
#define OFF_SIN  (size_t)(18612224)
#define OFF_QT   (size_t)(18874368)
#define OFF_KT   (size_t)(35651584)
#define OFF_VT   (size_t)(44040192)
#define OFF_Y    (size_t)(52428800)
#define WS_NEEDED (size_t)(69206016)

__device__ inline void mfma16(f32x4& acc, bf16x8 a, bf16x8 b) {
    acc = __builtin_amdgcn_mfma_f32_16x16x32_bf16(a, b, acc, 0, 0, 0);
}

// async global->LDS, 16B per lane. LDS dest is wave-uniform base + lane*16;
// the per-lane GLOBAL address carries the permutation (m173 pattern).
typedef const __attribute__((address_space(1))) uint8_t* gas_ptr;
typedef __attribute__((address_space(3))) uint8_t* las_ptr;
__device__ inline void gload16(const bf16* g, bf16* l) {
    __builtin_amdgcn_global_load_lds((gas_ptr)(const void*)g, (las_ptr)(void*)l, 16, 0, 0);
}

// ---------------- prep: fp32 -> bf16 casts + stacked W + rope tables ----------------
__global__ void prep_kernel(const float* __restrict__ x, const float* __restrict__ wq,
                            const float* __restrict__ wk, const float* __restrict__ wv,
                            const float* __restrict__ wp,
                            bf16* __restrict__ xb, bf16* __restrict__ wqkv,
                            bf16* __restrict__ wpb, float* __restrict__ cosT,
                            float* __restrict__ sinT) {
    int tid = blockIdx.x * blockDim.x + threadIdx.x;
    int stride = gridDim.x * blockDim.x;
    for (int i = tid; i < BT_ * DIM_; i += stride) xb[i] = (bf16)x[i];
    for (int i = tid; i < 1024 * 512; i += stride) {
        int j = i >> 9, k = i & 511;
        float v;
        if (j < 512) v = wq[i];
        else if (j < 768) v = wk[(j - 512) * 512 + k];
        else v = wv[(j - 768) * 512 + k];
        wqkv[i] = (bf16)v;
    }
    for (int i = tid; i < 512 * 512; i += stride) wpb[i] = (bf16)wp[i];
    for (int i = tid; i < T_SEQ * 32; i += stride) {
        int t = i >> 5, d = i & 31;
        float inv = powf(10000.0f, -(float)d * (1.0f / 32.0f));
        float f = (float)t * inv;
        cosT[i] = cosf(f);
        sinT[i] = sinf(f);
    }
}

// ---------------- QKV GEMM + fused RMSNorm + RoPE epilogue ----------------
__global__ __launch_bounds__(256) void qkv_gemm(const bf16* __restrict__ A,
                                                const bf16* __restrict__ B,
                                                bf16* __restrict__ qt,
                                                bf16* __restrict__ kt,
                                                bf16* __restrict__ vt,
                                                const float* __restrict__ cosT,
                                                const float* __restrict__ sinT) {
    __shared__ __align__(16) char smem[34816]; // loop: A(16K)+B(16K); epilogue: 4x 64x66 bf16
    bf16* As = (bf16*)smem;
    bf16* Bs = (bf16*)(smem + 16384);
    const int tid = threadIdx.x, lane = tid & 63, wid = tid >> 6;
    const int wr = wid >> 1, wc = wid & 1;
    const int lm = lane & 15, hi = lane >> 4;
    const int bid = blockIdx.x;
    const int swz = (bid & 7) * 128 + (bid >> 3); // XCD swizzle: each XCD owns a col stripe
    const int brow = (swz & 127) * 128;
    const int bcol = (swz >> 7) * 128;

    f32x4 acc[4][4] = {};
    for (int k0 = 0; k0 < 512; k0 += 64) {
        __syncthreads();
#pragma unroll
        for (int i = 0; i < 4; ++i) {
            int c = i * 256 + tid;
            int slot = c >> 6, l = c & 63;
            int row = (slot >> 1) * 16 + (l & 15);
            int kc = (slot & 1) * 32 + (l >> 4) * 8;
            gload16(A + (size_t)(brow + row) * 512 + k0 + kc, As + c * 8);
            gload16(B + (size_t)(bcol + row) * 512 + k0 + kc, Bs + c * 8);
        }
        asm volatile("s_waitcnt vmcnt(0)" ::: "memory");
        __syncthreads();
#pragma unroll
        for (int kk = 0; kk < 2; ++kk) {
            bf16x8 af[4], bfr[4];
#pragma unroll
            for (int m = 0; m < 4; ++m)
                af[m] = *(const bf16x8*)(As + (((wr * 4 + m) * 2 + kk) * 64 + lane) * 8);
#pragma unroll
            for (int n = 0; n < 4; ++n)
                bfr[n] = *(const bf16x8*)(Bs + (((wc * 4 + n) * 2 + kk) * 64 + lane) * 8);
            __builtin_amdgcn_s_setprio(1);
#pragma unroll
            for (int m = 0; m < 4; ++m)
#pragma unroll
                for (int n = 0; n < 4; ++n) mfma16(acc[m][n], af[m], bfr[n]);
            __builtin_amdgcn_s_setprio(0);
        }
    }
    __syncthreads(); // staging reads complete; smem now the transpose buffer

    bf16* Tb = (bf16*)smem + wid * 4224; // 64 x 66 per wave
    const int wcol = bcol + wc * 64;     // 64-aligned -> whole wave is one head type
    const int ctype = (wcol < 512) ? 0 : (wcol < 768 ? 1 : 2);

    if (ctype < 2) {
#pragma unroll
        for (int m = 0; m < 4; ++m)
#pragma unroll
            for (int r = 0; r < 4; ++r) {
                float v0 = acc[m][0][r], v1 = acc[m][1][r];
                float v2 = acc[m][2][r], v3 = acc[m][3][r];
                float ss = v0 * v0 + v1 * v1 + v2 * v2 + v3 * v3;
                ss += __shfl_xor(ss, 1);
                ss += __shfl_xor(ss, 2);
                ss += __shfl_xor(ss, 4);
                ss += __shfl_xor(ss, 8);
                float rinv = rsqrtf(ss * (1.0f / 64.0f) + EPS_);
                v0 *= rinv; v1 *= rinv; v2 *= rinv; v3 *= rinv;
                int rl = m * 16 + hi * 4 + r;
                int t = (brow + wr * 64 + rl) & (T_SEQ - 1);
                float c0 = cosT[t * 32 + lm], s0 = sinT[t * 32 + lm];
                float c1 = cosT[t * 32 + 16 + lm], s1 = sinT[t * 32 + 16 + lm];
                float o0 = v0 * c0 + v2 * s0;
                float o2 = v2 * c0 - v0 * s0;
                float o1 = v1 * c1 + v3 * s1;
                float o3 = v3 * c1 - v1 * s1;
                if (ctype == 0) { o0 *= QSCALE; o1 *= QSCALE; o2 *= QSCALE; o3 *= QSCALE; }
                Tb[rl * 66 + lm]      = (bf16)o0;
                Tb[rl * 66 + 16 + lm] = (bf16)o1;
                Tb[rl * 66 + 32 + lm] = (bf16)o2;
                Tb[rl * 66 + 48 + lm] = (bf16)o3;
            }
    } else {
#pragma unroll
        for (int m = 0; m < 4; ++m)
#pragma unroll
            for (int n = 0; n < 4; ++n)
#pragma unroll
                for (int r = 0; r < 4; ++r)
                    Tb[(n * 16 + lm) * 66 + m * 16 + hi * 4 + r] = (bf16)acc[m][n][r];
    }
    __syncthreads();

    const int i0 = brow + wr * 64;
    const int b = i0 >> 11, tt = i0 & (T_SEQ - 1);
#pragma unroll
    for (int p = 0; p < 8; ++p) {
        int row = p * 8 + (lane >> 3);
        int ch = lane & 7;
        bf16x8 val = *(const bf16x8*)(Tb + row * 66 + ch * 8);
        if (ctype == 0) {
            int head = wcol >> 6;
            *(bf16x8*)(qt + ((size_t)((b << 3) + head) * T_SEQ + tt + row) * 64 + ch * 8) = val;
        } else if (ctype == 1) {
            int head = (wcol - 512) >> 6;
            *(bf16x8*)(kt + ((size_t)((b << 2) + head) * T_SEQ + tt + row) * 64 + ch * 8) = val;
        } else {
            int head = (wcol - 768) >> 6;
            *(bf16x8*)(vt + ((size_t)((b << 2) + head) * 64 + row) * T_SEQ + tt + ch * 8) = val;
        }
    }
}

// ---------------- causal GQA flash attention ----------------
// Fixed-max softmax (scores bounded by Cauchy-Schwarz after RMSNorm) + double-buffered
// K/V staging with counted vmcnt so next-tile loads fly during current-tile compute.
__global__ __launch_bounds__(256) void attn_kernel(const bf16* __restrict__ qt,
                                                   const bf16* __restrict__ kt,
                                                   const bf16* __restrict__ vt,
                                                   bf16* __restrict__ y) {
    __shared__ bf16 Klds[2][4096];    // 8 frag-slots x 64 lanes x 8 elem, double-buffered
    __shared__ bf16 Vlds[2][4096];
    __shared__ bf16 Plds[4][32 * 72]; // per-wave P / O-transpose buffer, stride 72
    const int tid = threadIdx.x;
    const int lane = tid & 63, wid = tid >> 6;
    const int lm = lane & 15, hi = lane >> 4;
    const int bh = blockIdx.x & 63;
    const int p = 15 - (int)(blockIdx.x >> 6); // heavy-first
    const int b = bh >> 3, h = bh & 7, hv = h >> 1;
    const bf16* Q = qt + (size_t)bh * T_SEQ * HD_;
    const bf16* K = kt + (size_t)(b * NKV_ + hv) * T_SEQ * HD_;
    const bf16* V = vt + (size_t)(b * NKV_ + hv) * HD_ * T_SEQ;
    const int qB = p * 128;
    const int qw = qB + wid * 32;
    bf16* Pl = &Plds[wid][0];

    // per-thread staging base pointers (tile 0); chunk c -> slot=c>>6, l=c&63
    const int sl0 = tid >> 6, l0 = tid & 63;          // chunk c0 = tid
    const int gr0 = (sl0 >> 1) * 16 + (l0 & 15);
    const int gc0 = (sl0 & 1) * 32 + (l0 >> 4) * 8;
    const int sl1 = (256 + tid) >> 6, l1 = tid & 63;  // chunk c1 = 256+tid
    const int gr1 = (sl1 >> 1) * 16 + (l1 & 15);
    const int gc1 = (sl1 & 1) * 32 + (l1 >> 4) * 8;
    const bf16* kg0 = K + (size_t)gr0 * HD_ + gc0;
    const bf16* kg1 = K + (size_t)gr1 * HD_ + gc1;
    const bf16* vg0 = V + (size_t)gr0 * T_SEQ + gc0;
    const bf16* vg1 = V + (size_t)gr1 * T_SEQ + gc1;
    bf16* kd0 = &Klds[0][0] + (size_t)tid * 8;
    bf16* kd1 = &Klds[0][0] + (size_t)(256 + tid) * 8;
    bf16* vd0 = &Vlds[0][0] + (size_t)tid * 8;
    bf16* vd1 = &Vlds[0][0] + (size_t)(256 + tid) * 8;

#define STAGE_KV(t, buf) do {                                    \
        size_t ko = (size_t)(t) * (64 * HD_), vo = (size_t)(t) * 64; \
        size_t bo = (size_t)(buf) * 4096;                        \
        gload16(kg0 + ko, kd0 + bo);                             \
        gload16(kg1 + ko, kd1 + bo);                             \
        gload16(vg0 + vo, vd0 + bo);                             \
        gload16(vg1 + vo, vd1 + bo);                             \
    } while (0)

    // Q fragments (B-side): lane holds Q[q=16*qm+lm][d = 32*kk + 8*hi + j]
    bf16x8 qf[2][2];
#pragma unroll
    for (int qm = 0; qm < 2; ++qm)
#pragma unroll
        for (int kk = 0; kk < 2; ++kk)
            qf[qm][kk] = *(const bf16x8*)(Q + (size_t)(qw + 16 * qm + lm) * HD_ + 32 * kk + 8 * hi);

    f32x4 o[2][4] = {};
    float lrow[2] = {0.f, 0.f};

    const int nt = (qB >> 6) + 2;
    STAGE_KV(0, 0);
    for (int t = 0; t < nt; ++t) {
        const int kv0 = t << 6;
        const int cur = t & 1;
        if (t + 1 < nt) {
            STAGE_KV(t + 1, cur ^ 1);
            asm volatile("s_waitcnt vmcnt(4)" ::: "memory"); // drain tile t's 4, keep t+1's flying
        } else {
            asm volatile("s_waitcnt vmcnt(0)" ::: "memory");
        }
        __syncthreads();

        if (kv0 <= qw + 31) { // wave-uniform: skip fully-masked tiles
            const bf16* Kb = &Klds[cur][0];
            const bf16* Vb = &Vlds[cur][0];
            // ---- QK^T (swapped): s[qm][n] rows = kv (16n+4hi+r), col = q (lm)
            f32x4 s[2][4] = {};
#pragma unroll
            for (int kk = 0; kk < 2; ++kk) {
                bf16x8 kf[4];
#pragma unroll
                for (int n = 0; n < 4; ++n)
                    kf[n] = *(const bf16x8*)(Kb + ((n * 2 + kk) * 64 + lane) * 8);
                __builtin_amdgcn_s_setprio(1);
#pragma unroll
                for (int qm = 0; qm < 2; ++qm)
#pragma unroll
                    for (int n = 0; n < 4; ++n) mfma16(s[qm][n], kf[n], qf[qm][kk]);
                __builtin_amdgcn_s_setprio(0);
            }
            const bool partial = (kv0 + 63 > qw);
#pragma unroll
            for (int qm = 0; qm < 2; ++qm) {
                const int qg = qw + 16 * qm + lm;
                float ps = 0.f;
                bf16x4 pw[4];
#pragma unroll
                for (int n = 0; n < 4; ++n)
#pragma unroll
                    for (int r = 0; r < 4; ++r) {
                        float xv = s[qm][n][r];
                        if (partial)
                            xv = ((kv0 + 16 * n + 4 * hi + r) <= qg) ? xv : NEG_INF;
                        float e = exp2f(xv - SMAX); // fixed max: no running max, no rescale
                        ps += e;
                        pw[n][r] = (bf16)e;
                    }
                ps += __shfl_xor(ps, 16);
                ps += __shfl_xor(ps, 32);
                lrow[qm] += ps;
#pragma unroll
                for (int n = 0; n < 4; ++n)
                    *(bf16x4*)(Pl + (16 * qm + lm) * 72 + 16 * n + 4 * hi) = pw[n];
            }
            // ---- PV (swapped): o[qm][nd] rows = d (16nd+4hi+r), col = q (lm)
#pragma unroll
            for (int kk = 0; kk < 2; ++kk) {
                bf16x8 vf[4], pf[2];
#pragma unroll
                for (int nd = 0; nd < 4; ++nd)
                    vf[nd] = *(const bf16x8*)(Vb + ((nd * 2 + kk) * 64 + lane) * 8);
#pragma unroll
                for (int qm = 0; qm < 2; ++qm)
                    pf[qm] = *(const bf16x8*)(Pl + (16 * qm + lm) * 72 + 32 * kk + 8 * hi);
                __builtin_amdgcn_s_setprio(1);
#pragma unroll
                for (int qm = 0; qm < 2; ++qm)
#pragma unroll
                    for (int nd = 0; nd < 4; ++nd) mfma16(o[qm][nd], vf[nd], pf[qm]);
                __builtin_amdgcn_s_setprio(0);
            }
        }
        __syncthreads(); // all waves done reading buf[cur] before t+2 overwrites it
    }
#undef STAGE_KV

    // epilogue: normalize, transpose O^T->O through per-wave LDS, coalesced y write
#pragma unroll
    for (int qm = 0; qm < 2; ++qm) {
        float rcl = 1.0f / lrow[qm];
#pragma unroll
        for (int nd = 0; nd < 4; ++nd) {
            bf16x4 ov;
#pragma unroll
            for (int r = 0; r < 4; ++r) ov[r] = (bf16)(o[qm][nd][r] * rcl);
            *(bf16x4*)(Pl + (16 * qm + lm) * 72 + nd * 16 + 4 * hi) = ov;
        }
    }
#pragma unroll
    for (int qm = 0; qm < 2; ++qm)
#pragma unroll
        for (int it = 0; it < 2; ++it) {
            int chunk = it * 64 + lane;
            int row = chunk >> 3, dc = (chunk & 7) * 8;
            bf16x8 val = *(const bf16x8*)(Pl + (16 * qm + row) * 72 + dc);
            *(bf16x8*)(y + (size_t)(b * T_SEQ + qw + 16 * qm + row) * DIM_ + h * HD_ + dc) = val;
        }
}

// ---------------- output projection: out[i][j] = sum_k Y[i][k]*Wp[j][k] ----------------
__global__ __launch_bounds__(256) void proj_gemm(const bf16* __restrict__ A,
                                                 const bf16* __restrict__ B,
                                                 float* __restrict__ out) {
    __shared__ __align__(16) char smem[32768];
    bf16* As = (bf16*)smem;
    bf16* Bs = (bf16*)(smem + 16384);
    const int tid = threadIdx.x, lane = tid & 63, wid = tid >> 6;
    const int wr = wid >> 1, wc = wid & 1;
    const int lm = lane & 15, hi = lane >> 4;
    const int bid = blockIdx.x;
    const int swz = (bid & 7) * 64 + (bid >> 3);
    const int brow = (swz & 127) * 128;
    const int bcol = (swz >> 7) * 128;

    f32x4 acc[4][4] = {};
    for (int k0 = 0; k0 < 512; k0 += 64) {
        __syncthreads();
#pragma unroll
        for (int i = 0; i < 4; ++i) {
            int c = i * 256 + tid;
            int slot = c >> 6, l = c & 63;
            int row = (slot >> 1) * 16 + (l & 15);
            int kc = (slot & 1) * 32 + (l >> 4) * 8;
            gload16(A + (size_t)(brow + row) * 512 + k0 + kc, As + c * 8);
            gload16(B + (size_t)(bcol + row) * 512 + k0 + kc, Bs + c * 8);
        }
        asm volatile("s_waitcnt vmcnt(0)" ::: "memory");
        __syncthreads();
#pragma unroll
        for (int kk = 0; kk < 2; ++kk) {
            bf16x8 af[4], bfr[4];
#pragma unroll
            for (int m = 0; m < 4; ++m)
                af[m] = *(const bf16x8*)(As + (((wr * 4 + m) * 2 + kk) * 64 + lane) * 8);
#pragma unroll
            for (int n = 0; n < 4; ++n)
                bfr[n] = *(const bf16x8*)(Bs + (((wc * 4 + n) * 2 + kk) * 64 + lane) * 8);
            __builtin_amdgcn_s_setprio(1);
#pragma unroll
            for (int m = 0; m < 4; ++m)
#pragma unroll
                for (int n = 0; n < 4; ++n) mfma16(acc[m][n], af[m], bfr[n]);
            __builtin_amdgcn_s_setprio(0);
        }
    }
#pragma unroll
    for (int m = 0; m < 4; ++m)
#pragma unroll
        for (int n = 0; n < 4; ++n)
#pragma unroll
            for (int r = 0; r < 4; ++r) {
                int i = brow + wr * 64 + m * 16 + hi * 4 + r;
                int j = bcol + wc * 64 + n * 16 + lm;
                out[(size_t)i * DIM_ + j] = acc[m][n][r];
            }
}

extern "C" void kernel_launch(void* const* d_in, const int* in_sizes, int n_in,
                              void* d_out, int out_size, void* d_ws, size_t ws_size,
                              hipStream_t stream) {
    const float* x  = (const float*)d_in[0];
    const float* wq = (const float*)d_in[1];
    const float* wk = (const float*)d_in[2];
    const float* wv = (const float*)d_in[3];
    const float* wp = (const float*)d_in[4];
    if (ws_size < WS_NEEDED) return;

    char* ws = (char*)d_ws;
    bf16* xb    = (bf16*)(ws + OFF_XB);
    bf16* wqkv  = (bf16*)(ws + OFF_WQKV);
    bf16* wpb   = (bf16*)(ws + OFF_WP);
    float* cosT = (float*)(ws + OFF_COS);
    float* sinT = (float*)(ws + OFF_SIN);
    bf16* qt    = (bf16*)(ws + OFF_QT);
    bf16* kt    = (bf16*)(ws + OFF_KT);
    bf16* vt    = (bf16*)(ws + OFF_VT);
    bf16* y     = (bf16*)(ws + OFF_Y);

    prep_kernel<<<2048, 256, 0, stream>>>(x, wq, wk, wv, wp, xb, wqkv, wpb, cosT, sinT);

    qkv_gemm<<<1024, 256, 0, stream>>>(xb, wqkv, qt, kt, vt, cosT, sinT);

    attn_kernel<<<dim3(16 * 64), 256, 0, stream>>>(qt, kt, vt, y);

    proj_gemm<<<512, 256, 0, stream>>>(y, wpb, (float*)d_out);
}